// Round 1
// baseline (1608.380 us; speedup 1.0000x reference)
//
#include <hip/hip_runtime.h>
#include <math.h>

// Model constants (shapes from reference)
static constexpr int HID = 128;
static constexpr int H   = 8;
static constexpr int DH  = 16;
static constexpr int LAY = 4;
static constexpr int K   = 100;

__device__ __forceinline__ float leaky(float x){ return x > 0.f ? x : 0.2f*x; }
__device__ __forceinline__ float elu1(float x){ return x > 0.f ? x : expm1f(x); }

// ---------------- utility ----------------
__global__ void k_zero(int* p, int n){
  int i = blockIdx.x*blockDim.x + threadIdx.x;
  if (i < n) p[i] = 0;
}

// ---------------- CSR build (counting sort by dst) ----------------
__global__ void k_deg(const int* __restrict__ dst, int* __restrict__ deg, int E){
  int e = blockIdx.x*blockDim.x + threadIdx.x;
  if (e < E) atomicAdd(&deg[dst[e]], 1);
}

// chunked scan: 1024 elems/block, 256 threads x 4
__global__ void k_scan1(const int* __restrict__ deg, int* __restrict__ row_ptr,
                        int* __restrict__ bsum, int n){
  __shared__ int s[256];
  int tid = threadIdx.x;
  int base = blockIdx.x*1024 + tid*4;
  int v0 = (base+0 < n) ? deg[base+0] : 0;
  int v1 = (base+1 < n) ? deg[base+1] : 0;
  int v2 = (base+2 < n) ? deg[base+2] : 0;
  int v3 = (base+3 < n) ? deg[base+3] : 0;
  int t1 = v0+v1, t2 = t1+v2, t3 = t2+v3;
  s[tid] = t3;
  __syncthreads();
  for (int off=1; off<256; off<<=1){
    int t = (tid >= off) ? s[tid-off] : 0;
    __syncthreads();
    s[tid] += t;
    __syncthreads();
  }
  int excl = tid ? s[tid-1] : 0;
  if (base+0 < n) row_ptr[1+base+0] = excl + v0;
  if (base+1 < n) row_ptr[1+base+1] = excl + t1;
  if (base+2 < n) row_ptr[1+base+2] = excl + t2;
  if (base+3 < n) row_ptr[1+base+3] = excl + t3;
  if (tid == 255) bsum[blockIdx.x] = s[255];
}

__global__ void k_scan2(int* bsum, int nb){
  if (threadIdx.x == 0 && blockIdx.x == 0){
    int run = 0;
    for (int i=0;i<nb;i++){ int t = bsum[i]; bsum[i] = run; run += t; }
  }
}

__global__ void k_scan3(int* row_ptr, const int* __restrict__ bsum, int n){
  int i = blockIdx.x*blockDim.x + threadIdx.x;
  if (i < n) row_ptr[1+i] += bsum[i >> 10];
  if (i == 0) row_ptr[0] = 0;
}

__global__ void k_scatter(const int* __restrict__ src, const int* __restrict__ dst,
                          const int* __restrict__ row_ptr, int* __restrict__ fill,
                          int* __restrict__ srcs, int E){
  int e = blockIdx.x*blockDim.x + threadIdx.x;
  if (e < E){
    int d = dst[e];
    int pos = row_ptr[d] + atomicAdd(&fill[d], 1);
    srcs[pos] = src[e];
  }
}

// ---------------- fused xl/xr GEMM: [N,128] @ [128,128] x2 ----------------
// block = 256 threads: tid/128 selects {wl,wr}, tid%128 = output column.
// 32 rows of x staged in LDS as float4; LDS reads are wave-uniform (broadcast).
__global__ __launch_bounds__(256) void k_gemm2(const float* __restrict__ x,
    const float* __restrict__ wl, const float* __restrict__ wr,
    float* __restrict__ xl, float* __restrict__ xr, int nrows){
  __shared__ float4 xs[32][32];
  int tid = threadIdx.x;
  int row0 = blockIdx.x * 32;
  for (int i = tid; i < 1024; i += 256){
    int r = i >> 5, k4 = i & 31;
    int row = row0 + r;
    float4 v = make_float4(0.f,0.f,0.f,0.f);
    if (row < nrows) v = reinterpret_cast<const float4*>(x)[row*32 + k4];
    xs[r][k4] = v;
  }
  __syncthreads();
  int g = tid >> 7;          // 0 -> wl, 1 -> wr
  int c = tid & 127;
  const float* w = g ? wr : wl;
  float acc[32];
  #pragma unroll
  for (int r=0;r<32;r++) acc[r] = 0.f;
  for (int k4=0;k4<32;k4++){
    float w0 = w[(4*k4+0)*128 + c];
    float w1 = w[(4*k4+1)*128 + c];
    float w2 = w[(4*k4+2)*128 + c];
    float w3 = w[(4*k4+3)*128 + c];
    #pragma unroll
    for (int r=0;r<32;r++){
      float4 xv = xs[r][k4];
      acc[r] += xv.x*w0 + xv.y*w1 + xv.z*w2 + xv.w*w3;
    }
  }
  float* out = g ? xr : xl;
  #pragma unroll
  for (int r=0;r<32;r++){
    int row = row0 + r;
    if (row < nrows) out[row*128 + c] = acc[r];
  }
}

// ---------------- GATv2 edge pass: one wave per dst node ----------------
// lane l owns feature dims {2l, 2l+1}; head h = l/8 (16 dims per head across
// 8 lanes). Online softmax per head; xl[src] read once per edge (512B, float2
// coalesced across the wave).
__global__ __launch_bounds__(256) void k_gat(const float* __restrict__ xl,
    const float* __restrict__ xr, const int* __restrict__ row_ptr,
    const int* __restrict__ srcs, const float* __restrict__ att,
    const float* __restrict__ bias, float* __restrict__ xout, int n){
  int wid  = (blockIdx.x * blockDim.x + threadIdx.x) >> 6;
  int lane = threadIdx.x & 63;
  if (wid >= n) return;
  const float2* xl2 = reinterpret_cast<const float2*>(xl);
  float2 xrv = reinterpret_cast<const float2*>(xr)[wid*64 + lane];
  float a0 = att[2*lane], a1 = att[2*lane+1];
  float m = -INFINITY, ssum = 0.f, acc0 = 0.f, acc1 = 0.f;
  int start = row_ptr[wid], end = row_ptr[wid+1];
  for (int base = start; base < end; base += 64){
    int cnt = end - base; if (cnt > 64) cnt = 64;
    int sv = (lane < cnt) ? srcs[base + lane] : 0;
    for (int t = 0; t < cnt; ++t){
      int sidx = __shfl(sv, t);
      float2 v = xl2[sidx*64 + lane];
      float e = a0*leaky(v.x + xrv.x) + a1*leaky(v.y + xrv.y);
      e += __shfl_xor(e, 1);
      e += __shfl_xor(e, 2);
      e += __shfl_xor(e, 4);          // per-head score now in all 8 lanes
      float mn = fmaxf(m, e);
      float scale = expf(m - mn);      // 0 on first edge (m=-inf)
      float p = expf(e - mn);
      ssum = ssum*scale + p;
      acc0 = acc0*scale + p*v.x;
      acc1 = acc1*scale + p*v.y;
      m = mn;
    }
  }
  float o0 = 0.f, o1 = 0.f;
  if (end > start){ o0 = acc0/ssum; o1 = acc1/ssum; }
  o0 = elu1(o0 + bias[2*lane]);
  o1 = elu1(o1 + bias[2*lane+1]);
  reinterpret_cast<float2*>(xout)[wid*64 + lane] = make_float2(o0, o1);
}

// ---------------- graph node ranges (batch is sorted) ----------------
__global__ void k_graph_ptr(const int* __restrict__ batch, int* __restrict__ gp,
                            int n, int nb){
  int b = blockIdx.x*blockDim.x + threadIdx.x;
  if (b > nb) return;
  int lo = 0, hi = n;
  while (lo < hi){ int mid = (lo+hi)>>1; if (batch[mid] < b) lo = mid+1; else hi = mid; }
  gp[b] = lo;   // for b==nb this yields n
}

// ---------------- gated sum-pool + max-pool: one wave per graph ----------------
__global__ __launch_bounds__(256) void k_pool(const float* __restrict__ x,
    const int* __restrict__ gp, const float* __restrict__ read_w,
    const float* __restrict__ read_b, float* __restrict__ mol, int nb){
  int w    = (blockIdx.x * blockDim.x + threadIdx.x) >> 6;
  int lane = threadIdx.x & 63;
  if (w >= nb) return;
  const float2* x2 = reinterpret_cast<const float2*>(x);
  float rw0 = read_w[2*lane], rw1 = read_w[2*lane+1];
  float rb = read_b[0];
  float s0=0.f, s1=0.f, m0=-INFINITY, m1=-INFINITY;
  int start = gp[w], end = gp[w+1];
  for (int nidx = start; nidx < end; ++nidx){
    float2 v = x2[nidx*64 + lane];
    float d = v.x*rw0 + v.y*rw1;
    d += __shfl_xor(d, 1);  d += __shfl_xor(d, 2);  d += __shfl_xor(d, 4);
    d += __shfl_xor(d, 8);  d += __shfl_xor(d, 16); d += __shfl_xor(d, 32);
    float gate = 1.f/(1.f + expf(-(d + rb)));
    s0 += gate*v.x;  s1 += gate*v.y;
    m0 = fmaxf(m0, v.x);  m1 = fmaxf(m1, v.y);
  }
  if (end <= start){ m0 = 0.f; m1 = 0.f; }   // empty graph: isfinite guard
  mol[w*256 + 2*lane]       = s0;
  mol[w*256 + 2*lane+1]     = s1;
  mol[w*256 + 128 + 2*lane]   = m0;
  mol[w*256 + 128 + 2*lane+1] = m1;
}

// ---------------- Boltzmann + MLP head: one block (128 thr) per graph ----------------
__global__ __launch_bounds__(128) void k_head(const float* __restrict__ mol,
    const float* __restrict__ temps, const float* __restrict__ en_w,
    const float* __restrict__ en_b, const float* __restrict__ w1,
    const float* __restrict__ b1, const float* __restrict__ w2,
    const float* __restrict__ b2, float* __restrict__ out, int nb){
  __shared__ float molS[256];
  __shared__ float red[128];
  __shared__ float distS[128];
  __shared__ float hS[64];
  int b = blockIdx.x, tid = threadIdx.x;
  if (b >= nb) return;
  molS[tid]       = mol[b*256 + tid];
  molS[tid + 128] = mol[b*256 + 128 + tid];
  __syncthreads();
  float z = -INFINITY;
  if (tid < K){
    float acc = en_b[tid];
    for (int j=0;j<256;j++) acc += molS[j]*en_w[j*K + tid];
    z = -acc / temps[b];
  }
  red[tid] = z; __syncthreads();
  for (int off=64; off>0; off>>=1){
    if (tid < off) red[tid] = fmaxf(red[tid], red[tid+off]);
    __syncthreads();
  }
  float mx = red[0]; __syncthreads();
  float ex = (tid < K) ? expf(z - mx) : 0.f;
  red[tid] = ex; __syncthreads();
  for (int off=64; off>0; off>>=1){
    if (tid < off) red[tid] += red[tid+off];
    __syncthreads();
  }
  float denom = red[0];
  distS[tid] = ex / denom;
  __syncthreads();
  if (tid < 64){
    float acc = b1[tid];
    for (int k=0;k<K;k++) acc += distS[k]*w1[k*64 + tid];
    hS[tid] = elu1(acc);
  }
  __syncthreads();
  red[tid] = (tid < 64) ? hS[tid]*w2[tid] : 0.f;
  __syncthreads();
  for (int off=32; off>0; off>>=1){
    if (tid < off) red[tid] += red[tid+off];
    __syncthreads();
  }
  if (tid == 0) out[b] = red[0] + b2[0];
}

// ---------------- launch ----------------
extern "C" void kernel_launch(void* const* d_in, const int* in_sizes, int n_in,
                              void* d_out, int out_size, void* d_ws, size_t ws_size,
                              hipStream_t stream){
  const float* x0    = (const float*)d_in[0];
  const int*   ei    = (const int*)  d_in[1];
  const int*   batch = (const int*)  d_in[2];
  const float* temps = (const float*)d_in[3];
  const float* wl    = (const float*)d_in[4];
  const float* wr    = (const float*)d_in[5];
  const float* att   = (const float*)d_in[6];
  const float* gatb  = (const float*)d_in[7];
  const float* read_w= (const float*)d_in[8];
  const float* read_b= (const float*)d_in[9];
  const float* en_w  = (const float*)d_in[10];
  const float* en_b  = (const float*)d_in[11];
  const float* w1    = (const float*)d_in[12];
  const float* b1    = (const float*)d_in[13];
  const float* w2    = (const float*)d_in[14];
  const float* b2    = (const float*)d_in[15];
  float* out = (float*)d_out;

  const int N = in_sizes[0] / HID;
  const int E = in_sizes[1] / 2;
  const int B = in_sizes[3];
  const int* src = ei;
  const int* dst = ei + E;

  char* ws = (char*)d_ws;
  size_t off = 0;
  auto alloc = [&](size_t bytes)->char*{
    char* p = ws + off; off += (bytes + 255) & ~size_t(255); return p;
  };
  float* xl    = (float*)alloc(sizeof(float)*(size_t)N*HID);
  float* xr    = (float*)alloc(sizeof(float)*(size_t)N*HID);
  float* xb    = (float*)alloc(sizeof(float)*(size_t)N*HID);
  float* mol   = (float*)alloc(sizeof(float)*(size_t)B*2*HID);
  int* row_ptr = (int*)alloc(sizeof(int)*(size_t)(N+1));
  int* deg     = (int*)alloc(sizeof(int)*(size_t)N);
  int* fill    = (int*)alloc(sizeof(int)*(size_t)N);
  int* srcs    = (int*)alloc(sizeof(int)*(size_t)E);
  int* bsum    = (int*)alloc(sizeof(int)*1024);
  int* gp      = (int*)alloc(sizeof(int)*(size_t)(B+1));

  // --- CSR by dst (once per call; reused by all 4 layers) ---
  int nchunk = (N + 1023) / 1024;
  k_zero<<<(N+255)/256, 256, 0, stream>>>(deg, N);
  k_zero<<<(N+255)/256, 256, 0, stream>>>(fill, N);
  k_deg<<<(E+255)/256, 256, 0, stream>>>(dst, deg, E);
  k_scan1<<<nchunk, 256, 0, stream>>>(deg, row_ptr, bsum, N);
  k_scan2<<<1, 1, 0, stream>>>(bsum, nchunk);
  k_scan3<<<(N+255)/256, 256, 0, stream>>>(row_ptr, bsum, N);
  k_scatter<<<(E+255)/256, 256, 0, stream>>>(src, dst, row_ptr, fill, srcs, E);

  // --- 4 GATv2 layers ---
  const float* xin = x0;
  for (int l = 0; l < LAY; ++l){
    k_gemm2<<<(N+31)/32, 256, 0, stream>>>(xin, wl + (size_t)l*HID*HID,
                                           wr + (size_t)l*HID*HID, xl, xr, N);
    k_gat<<<(N+3)/4, 256, 0, stream>>>(xl, xr, row_ptr, srcs,
                                       att + (size_t)l*H*DH, gatb + (size_t)l*HID, xb, N);
    xin = xb;
  }

  // --- readout + head ---
  k_graph_ptr<<<(B+1+255)/256, 256, 0, stream>>>(batch, gp, N, B);
  k_pool<<<(B+3)/4, 256, 0, stream>>>(xb, gp, read_w, read_b, mol, B);
  k_head<<<B, 128, 0, stream>>>(mol, temps, en_w, en_b, w1, b1, w2, b2, out, B);
}